// Round 2
// baseline (1033.688 us; speedup 1.0000x reference)
//
#include <hip/hip_runtime.h>
#include <hip/hip_bf16.h>

#define NPOS 49
#define NH 8
#define DIMC 384
#define VDC 512
#define SCALE_QK 0.17677669529663687f

typedef unsigned short u16;
typedef __attribute__((ext_vector_type(8))) short bf16x8_t;
typedef __attribute__((ext_vector_type(4))) float f32x4_t;

__device__ __forceinline__ u16 f2bf(float f) {
    unsigned u = __float_as_uint(f);
    u = (u + 0x7fffu + ((u >> 16) & 1u)) >> 16;
    return (u16)u;
}
__device__ __forceinline__ float bf2f(u16 b) {
    return __uint_as_float(((unsigned)b) << 16);
}

__global__ __launch_bounds__(256) void prep_kernel(
    const float* __restrict__ pw, const float* __restrict__ pj,
    const float* __restrict__ ab, const int* __restrict__ bidx,
    u16* __restrict__ wpw, u16* __restrict__ wpj, float* __restrict__ biasf)
{
    int i = blockIdx.x * 256 + threadIdx.x;
    if (i < 1024 * 384) wpw[i] = f2bf(pw[i]);
    if (i < 384 * 512)  wpj[i] = f2bf(pj[i]);
    if (i < 8 * 49 * 49) {
        int h = i / (49 * 49);
        int nm = i - h * (49 * 49);
        biasf[i] = ab[h * 49 + bidx[nm]];
    }
}

// One block per batch element. 1024 threads = 16 waves (4 waves/SIMD at
// 1 block/CU; the R1 512-thread version sat at 2 waves/SIMD, latency-bound).
// LDS (u16 units): region A [0, 31360): s_x [64][392] -> s_q [8*49][40] + s_k
//   (at 15680) -> s_P [8*49][72]; region B [31360, 68224): s_v [512][72] ->
//   s_out2 [pos][520]. Total 136,448 B.
__global__ __launch_bounds__(1024) void fused_kernel(
    const float* __restrict__ x,
    const float* __restrict__ pwb,
    const float* __restrict__ dww,
    const float* __restrict__ bng, const float* __restrict__ bnb,
    const float* __restrict__ bnm, const float* __restrict__ bnv,
    const float* __restrict__ pjb,
    const u16* __restrict__ wpw, const u16* __restrict__ wpj,
    const float* __restrict__ biasf,
    float* __restrict__ out)
{
    __shared__ u16 lds[68224];
    const int tid  = threadIdx.x;
    const int b    = blockIdx.x;
    const int wv   = tid >> 6;    // 0..15
    const int lane = tid & 63;
    const int quad = lane >> 4;
    const int l16  = lane & 15;

    u16* s_x  = lds;            // [64][392] bf16 (rows 0..48 valid)
    u16* s_q  = lds;            // [(h*49+pos)][40], d in [0,32), pre-scaled
    u16* s_k  = lds + 15680;
    u16* s_P  = lds;            // [(h*49+q)][72], key in [0,64)
    u16* s_v  = lds + 31360;    // [512][72], pos in [0,49), pads zeroed
    u16* s_o2 = lds + 31360;    // [pos][520], c in [0,512)

    // ---- stage 0: x -> LDS bf16 (float4 loads); zero s_v pad cols ----
    const float4* xb4 = (const float4*)(x + (size_t)b * (NPOS * DIMC));
    for (int i = tid; i < (NPOS * DIMC) / 4; i += 1024) {
        float4 t = xb4[i];
        int n = i / 96;                 // 96 float4 per row of 384
        int c = (i - n * 96) * 4;
        u16* d = s_x + n * 392 + c;
        d[0] = f2bf(t.x); d[1] = f2bf(t.y); d[2] = f2bf(t.z); d[3] = f2bf(t.w);
    }
    for (int i = tid; i < 512 * 23; i += 1024) {
        int c = i / 23, j = i - c * 23;
        s_v[c * 72 + 49 + j] = 0;
    }
    __syncthreads();

    // ---- stage 1: pwconv  h[1024][49] = W(1024x384) . x^T ----
    // Wave w owns 64 output channels [w*64, w*64+64).
    f32x4_t acc[4][4];
    #pragma unroll
    for (int nt = 0; nt < 4; ++nt)
        #pragma unroll
        for (int mt = 0; mt < 4; ++mt)
            acc[nt][mt] = (f32x4_t){0.f, 0.f, 0.f, 0.f};

    #pragma unroll
    for (int ks = 0; ks < 12; ++ks) {
        const int k0 = ks * 32 + quad * 8;
        bf16x8_t afr[4];
        #pragma unroll
        for (int mt = 0; mt < 4; ++mt)
            afr[mt] = *(const bf16x8_t*)(s_x + (mt * 16 + l16) * 392 + k0);
        #pragma unroll
        for (int nt = 0; nt < 4; ++nt) {
            const int och = wv * 64 + nt * 16 + l16;
            bf16x8_t bfr = *(const bf16x8_t*)(wpw + och * 384 + k0);
            #pragma unroll
            for (int mt = 0; mt < 4; ++mt)
                acc[nt][mt] = __builtin_amdgcn_mfma_f32_16x16x32_bf16(
                    afr[mt], bfr, acc[nt][mt], 0, 0, 0);
        }
    }
    __syncthreads();  // x dead; region A becomes q/k

    // D-write: +bias (and fold SCALE_QK into q), route to q/k/v.
    #pragma unroll
    for (int nt = 0; nt < 4; ++nt) {
        const int och = wv * 64 + nt * 16 + l16;
        const float bias = pwb[och];
        const float mul = (och < 256) ? SCALE_QK : 1.0f;
        u16* dst;
        int stride;
        if (och < 256)      { dst = s_q + ((och >> 5) * 49) * 40 + (och & 31); stride = 40; }
        else if (och < 512) { int o2 = och - 256;
                              dst = s_k + ((o2 >> 5) * 49) * 40 + (o2 & 31); stride = 40; }
        else                { dst = s_v + (och - 512) * 72; stride = 1; }
        #pragma unroll
        for (int mt = 0; mt < 4; ++mt)
            #pragma unroll
            for (int r = 0; r < 4; ++r) {
                int pos = mt * 16 + quad * 4 + r;
                if (pos < 49) dst[pos * stride] = f2bf((acc[nt][mt][r] + bias) * mul);
            }
    }
    __syncthreads();

    // ---- stage 2: depthwise 3x3 + BN + exact GELU residual ----
    // 2 threads per channel: half 0 -> output rows y=0..3, half 1 -> y=4..6.
    {
        const int c    = tid & 511;
        const int half = tid >> 9;
        const int base = half * 16;           // vv window [base, base+40)
        float vv[40];
        #pragma unroll
        for (int j = 0; j < 5; ++j) {
            bf16x8_t raw = *(const bf16x8_t*)(s_v + c * 72 + base + 8 * j);
            #pragma unroll
            for (int e = 0; e < 8; ++e) vv[j * 8 + e] = bf2f(raw[e]);
        }
        float tap[9];
        #pragma unroll
        for (int j = 0; j < 9; ++j) tap[j] = dww[c * 9 + j];
        const float scale = bng[c] * rsqrtf(bnv[c] + 1e-5f);
        const float shift = bnb[c] - bnm[c] * scale;
        const int y0 = half ? 4 : 0;
        const int ny = half ? 3 : 4;
        float res[28];
        for (int yy = 0; yy < 4; ++yy) {
            if (yy >= ny) break;
            const int y = y0 + yy;
            #pragma unroll
            for (int xx = 0; xx < 7; ++xx) {
                float s = 0.f;
                #pragma unroll
                for (int ky = 0; ky < 3; ++ky)
                    #pragma unroll
                    for (int kx = 0; kx < 3; ++kx) {
                        int iy = y + ky - 1, ix = xx + kx - 1;
                        if (iy >= 0 && iy < 7 && ix >= 0 && ix < 7)
                            s += tap[ky * 3 + kx] * vv[iy * 7 + ix - base];
                    }
                s = s * scale + shift;
                float g = 0.5f * s * (1.0f + erff(s * 0.70710678118654752f));
                res[yy * 7 + xx] = vv[y * 7 + xx - base] + g;
            }
        }
        __syncthreads();  // all reads done before cross-half writes land
        for (int yy = 0; yy < 4; ++yy) {
            if (yy >= ny) break;
            const int y = y0 + yy;
            #pragma unroll
            for (int xx = 0; xx < 7; ++xx)
                s_v[c * 72 + y * 7 + xx] = f2bf(res[yy * 7 + xx]);
        }
    }
    __syncthreads();

    // ---- stage 3: attention, 2 waves per head (split over M-tiles) ----
    {
        const int h    = wv >> 1;
        const int half = wv & 1;
        bf16x8_t qa[2], kfr[4];
        #pragma unroll
        for (int mtl = 0; mtl < 2; ++mtl)
            qa[mtl] = *(const bf16x8_t*)(s_q + (h * 49 + (half * 2 + mtl) * 16 + l16) * 40 + quad * 8);
        #pragma unroll
        for (int nt = 0; nt < 4; ++nt)
            kfr[nt] = *(const bf16x8_t*)(s_k + (h * 49 + nt * 16 + l16) * 40 + quad * 8);
        f32x4_t sc[2][4];
        #pragma unroll
        for (int mtl = 0; mtl < 2; ++mtl)
            #pragma unroll
            for (int nt = 0; nt < 4; ++nt) {
                f32x4_t z = (f32x4_t){0.f, 0.f, 0.f, 0.f};
                sc[mtl][nt] = __builtin_amdgcn_mfma_f32_16x16x32_bf16(qa[mtl], kfr[nt], z, 0, 0, 0);
            }

        float pvreg[2][4][4];  // [mtl][r][nt]
        #pragma unroll
        for (int mtl = 0; mtl < 2; ++mtl)
            #pragma unroll
            for (int r = 0; r < 4; ++r) {
                const int qrow = (half * 2 + mtl) * 16 + quad * 4 + r;
                float sv[4];
                #pragma unroll
                for (int nt = 0; nt < 4; ++nt) {
                    const int key = nt * 16 + l16;
                    float val;
                    if (key < 49 && qrow < 49)
                        val = sc[mtl][nt][r] + biasf[(h * 49 + qrow) * 49 + key];
                    else
                        val = -1e30f;  // masks pads + kills stale-LDS NaN
                    sv[nt] = val;
                }
                float mx = fmaxf(fmaxf(sv[0], sv[1]), fmaxf(sv[2], sv[3]));
                #pragma unroll
                for (int off = 1; off < 16; off <<= 1)
                    mx = fmaxf(mx, __shfl_xor(mx, off));
                float e0 = __expf(sv[0] - mx), e1 = __expf(sv[1] - mx);
                float e2 = __expf(sv[2] - mx), e3 = __expf(sv[3] - mx);
                float sum = e0 + e1 + e2 + e3;
                #pragma unroll
                for (int off = 1; off < 16; off <<= 1)
                    sum += __shfl_xor(sum, off);
                const float inv = 1.0f / sum;
                pvreg[mtl][r][0] = e0 * inv; pvreg[mtl][r][1] = e1 * inv;
                pvreg[mtl][r][2] = e2 * inv; pvreg[mtl][r][3] = e3 * inv;
            }
        __syncthreads();  // all q/k reads done before P overwrites region A
        #pragma unroll
        for (int mtl = 0; mtl < 2; ++mtl)
            #pragma unroll
            for (int r = 0; r < 4; ++r) {
                const int qrow = (half * 2 + mtl) * 16 + quad * 4 + r;
                if (qrow < 49) {
                    #pragma unroll
                    for (int nt = 0; nt < 4; ++nt)
                        s_P[(h * 49 + qrow) * 72 + nt * 16 + l16] = f2bf(pvreg[mtl][r][nt]);
                }
            }
        __syncthreads();

        // PV: out_h(49x64) = P(49x64keys) . V(64keys x 64)
        f32x4_t oa[2][4];
        #pragma unroll
        for (int mtl = 0; mtl < 2; ++mtl)
            #pragma unroll
            for (int nt = 0; nt < 4; ++nt)
                oa[mtl][nt] = (f32x4_t){0.f, 0.f, 0.f, 0.f};
        #pragma unroll
        for (int ksv = 0; ksv < 2; ++ksv) {
            const int kb0 = ksv * 32 + quad * 8;
            bf16x8_t pa[2], vb[4];
            #pragma unroll
            for (int mtl = 0; mtl < 2; ++mtl)
                pa[mtl] = *(const bf16x8_t*)(s_P + (h * 49 + (half * 2 + mtl) * 16 + l16) * 72 + kb0);
            #pragma unroll
            for (int nt = 0; nt < 4; ++nt)
                vb[nt] = *(const bf16x8_t*)(s_v + (h * 64 + nt * 16 + l16) * 72 + kb0);
            #pragma unroll
            for (int mtl = 0; mtl < 2; ++mtl)
                #pragma unroll
                for (int nt = 0; nt < 4; ++nt)
                    oa[mtl][nt] = __builtin_amdgcn_mfma_f32_16x16x32_bf16(
                        pa[mtl], vb[nt], oa[mtl][nt], 0, 0, 0);
        }
        __syncthreads();  // all s_v reads done before out2 overwrites region B
        #pragma unroll
        for (int mtl = 0; mtl < 2; ++mtl)
            #pragma unroll
            for (int nt = 0; nt < 4; ++nt)
                #pragma unroll
                for (int r = 0; r < 4; ++r) {
                    int pos = (half * 2 + mtl) * 16 + quad * 4 + r;
                    if (pos < 49)
                        s_o2[pos * 520 + h * 64 + nt * 16 + l16] = f2bf(oa[mtl][nt][r]);
                }
    }
    __syncthreads();

    // ---- stage 4: proj  out(49x384) = out2(49x512) . proj_w^T ----
    // 24 N-tiles of 16 over 16 waves: wave w owns tile w (and w+16 if w<8).
    {
        const int t1 = wv;
        const int t2 = wv + 16;
        const bool has2 = (t2 < 24);
        f32x4_t pacc[2][4];
        #pragma unroll
        for (int tt = 0; tt < 2; ++tt)
            #pragma unroll
            for (int mt = 0; mt < 4; ++mt)
                pacc[tt][mt] = (f32x4_t){0.f, 0.f, 0.f, 0.f};
        #pragma unroll
        for (int ks = 0; ks < 16; ++ks) {
            const int k0 = ks * 32 + quad * 8;
            bf16x8_t afr[4];
            #pragma unroll
            for (int mt = 0; mt < 4; ++mt)
                afr[mt] = *(const bf16x8_t*)(s_o2 + (mt * 16 + l16) * 520 + k0);
            bf16x8_t wb1 = *(const bf16x8_t*)(wpj + (t1 * 16 + l16) * 512 + k0);
            #pragma unroll
            for (int mt = 0; mt < 4; ++mt)
                pacc[0][mt] = __builtin_amdgcn_mfma_f32_16x16x32_bf16(
                    afr[mt], wb1, pacc[0][mt], 0, 0, 0);
            if (has2) {
                bf16x8_t wb2 = *(const bf16x8_t*)(wpj + (t2 * 16 + l16) * 512 + k0);
                #pragma unroll
                for (int mt = 0; mt < 4; ++mt)
                    pacc[1][mt] = __builtin_amdgcn_mfma_f32_16x16x32_bf16(
                        afr[mt], wb2, pacc[1][mt], 0, 0, 0);
            }
        }
        float* ob = out + (size_t)b * (NPOS * DIMC);
        #pragma unroll
        for (int tt = 0; tt < 2; ++tt) {
            if (tt == 1 && !has2) break;
            const int o = (tt ? t2 : t1) * 16 + l16;
            const float pb = pjb[o];
            #pragma unroll
            for (int mt = 0; mt < 4; ++mt)
                #pragma unroll
                for (int r = 0; r < 4; ++r) {
                    int pos = mt * 16 + quad * 4 + r;
                    if (pos < 49) ob[pos * 384 + o] = pacc[tt][mt][r] + pb;
                }
        }
    }
}

extern "C" void kernel_launch(void* const* d_in, const int* in_sizes, int n_in,
                              void* d_out, int out_size, void* d_ws, size_t ws_size,
                              hipStream_t stream)
{
    const float* x   = (const float*)d_in[0];
    const float* pw  = (const float*)d_in[1];
    const float* pwb = (const float*)d_in[2];
    const float* dww = (const float*)d_in[3];
    const float* bng = (const float*)d_in[4];
    const float* bnb = (const float*)d_in[5];
    const float* bnm = (const float*)d_in[6];
    const float* bnv = (const float*)d_in[7];
    const float* ab  = (const float*)d_in[8];
    const float* pj  = (const float*)d_in[9];
    const float* pjb = (const float*)d_in[10];
    const int*  bidx = (const int*)d_in[11];
    float* out = (float*)d_out;

    u16* wpw   = (u16*)d_ws;
    u16* wpj   = wpw + 1024 * 384;
    float* bia = (float*)(wpj + 384 * 512);

    const int nb = in_sizes[0] / (NPOS * DIMC);

    prep_kernel<<<1536, 256, 0, stream>>>(pw, pj, ab, bidx, wpw, wpj, bia);
    fused_kernel<<<nb, 1024, 0, stream>>>(x, pwb, dww, bng, bnb, bnm, bnv, pjb,
                                          wpw, wpj, bia, out);
}